// Round 1
// baseline (280.518 us; speedup 1.0000x reference)
//
#include <hip/hip_runtime.h>
#include <hip/hip_bf16.h>
#include <math.h>

#define NP 1024          // proposals
#define NC 81            // classes incl background
#define CF 80            // foreground classes
#define DET 100          // detections per image
#define SCORE_THRESH 0.05f
#define NMS_THRESH 0.5f
#define BBOX_CLIP 4.135166556742356f   // log(1000/16)
#define IMG_W 1333
#define IMG_H 800

#define NCAND (CF * DET)   // 8000
#define MSORT 8192         // pow2 >= NCAND

// ---------------------------------------------------------------------------
// Kernel 1: per-proposal softmax + box decode + clip.
// grid = NP blocks, 128 threads. Thread t (1..80) handles fg class t-1.
// scores_fg[j*NP + i], boxes_fg[(j*NP + i)*4 + k]   (class-major)
// ---------------------------------------------------------------------------
__global__ void softmax_decode_kernel(const float* __restrict__ logits,
                                      const float* __restrict__ rel,
                                      const float* __restrict__ props,
                                      float* __restrict__ scores_fg,
                                      float* __restrict__ boxes_fg) {
    const int i = blockIdx.x;
    const int t = threadIdx.x;   // 0..127
    __shared__ float red[128];

    float x = (t < NC) ? logits[i * NC + t] : -INFINITY;
    red[t] = x;
    __syncthreads();
    for (int s = 64; s > 0; s >>= 1) {
        if (t < s) red[t] = fmaxf(red[t], red[t + s]);
        __syncthreads();
    }
    const float m = red[0];
    __syncthreads();
    const float e = (t < NC) ? expf(x - m) : 0.0f;
    red[t] = e;
    __syncthreads();
    for (int s = 64; s > 0; s >>= 1) {
        if (t < s) red[t] += red[t + s];
        __syncthreads();
    }
    const float sum = red[0];

    if (t >= 1 && t < NC) {
        const int j = t - 1;                    // fg class index
        scores_fg[j * NP + i] = e / sum;

        // BoxCoder.decode (maskrcnn-benchmark legacy, TO_REMOVE=1)
        const float x1 = props[i * 4 + 0];
        const float y1 = props[i * 4 + 1];
        const float x2 = props[i * 4 + 2];
        const float y2 = props[i * 4 + 3];
        const float w  = x2 - x1 + 1.0f;
        const float h  = y2 - y1 + 1.0f;
        const float cx = x1 + 0.5f * w;
        const float cy = y1 + 0.5f * h;

        const float dx = rel[i * 4 * NC + 4 * t + 0] / 10.0f;
        const float dy = rel[i * 4 * NC + 4 * t + 1] / 10.0f;
        const float dw = fminf(rel[i * 4 * NC + 4 * t + 2] / 5.0f, BBOX_CLIP);
        const float dh = fminf(rel[i * 4 * NC + 4 * t + 3] / 5.0f, BBOX_CLIP);

        const float pcx = dx * w + cx;
        const float pcy = dy * h + cy;
        const float pw  = expf(dw) * w;
        const float ph  = expf(dh) * h;

        float bx1 = pcx - 0.5f * pw;
        float by1 = pcy - 0.5f * ph;
        float bx2 = pcx + 0.5f * pw - 1.0f;
        float by2 = pcy + 0.5f * ph - 1.0f;

        // clip_to_image
        bx1 = fminf(fmaxf(bx1, 0.0f), (float)(IMG_W - 1));
        bx2 = fminf(fmaxf(bx2, 0.0f), (float)(IMG_W - 1));
        by1 = fminf(fmaxf(by1, 0.0f), (float)(IMG_H - 1));
        by2 = fminf(fmaxf(by2, 0.0f), (float)(IMG_H - 1));

        float* bp = boxes_fg + (size_t)(j * NP + i) * 4;
        bp[0] = bx1; bp[1] = by1; bp[2] = bx2; bp[3] = by2;
    }
}

// ---------------------------------------------------------------------------
// Kernel 2: per-class sort + greedy NMS + emit top<=100 kept candidates.
// grid = CF blocks, 256 threads.
// ---------------------------------------------------------------------------
__global__ void class_nms_kernel(const float* __restrict__ scores_fg,
                                 const float* __restrict__ boxes_fg,
                                 float* __restrict__ cand_score,
                                 float* __restrict__ cand_box) {
    const int cls = blockIdx.x;   // fg class
    const int tid = threadIdx.x;  // 0..255

    __shared__ float          s[NP];
    __shared__ unsigned short id[NP];
    __shared__ float4         box[NP];
    __shared__ unsigned char  supp[NP];
    __shared__ int            Vsh;
    __shared__ int            keptRank[DET];
    __shared__ int            keptCnt;

    for (int t = tid; t < NP; t += blockDim.x) {
        s[t]  = scores_fg[cls * NP + t];
        id[t] = (unsigned short)t;
    }
    __syncthreads();

    // Bitonic sort: score desc, index asc on ties (== stable argsort(-s))
    for (int k = 2; k <= NP; k <<= 1) {
        for (int jj = k >> 1; jj > 0; jj >>= 1) {
            for (int t = tid; t < NP; t += blockDim.x) {
                const int ixj = t ^ jj;
                if (ixj > t) {
                    const float sa = s[t], sb = s[ixj];
                    const unsigned short ia = id[t], ib = id[ixj];
                    // tAfter: element t comes AFTER ixj in desired order
                    const bool tAfter = (sa < sb) || (sa == sb && ia > ib);
                    const bool dirAsc = ((t & k) == 0);
                    if (dirAsc ? tAfter : !tAfter) {
                        s[t] = sb; s[ixj] = sa;
                        id[t] = ib; id[ixj] = ia;
                    }
                }
            }
            __syncthreads();
        }
    }

    // V = number of sorted scores > thresh (sorted desc => prefix)
    if (tid == 0) Vsh = NP;
    __syncthreads();
    for (int t = tid; t < NP; t += blockDim.x)
        if (!(s[t] > SCORE_THRESH)) atomicMin(&Vsh, t);
    __syncthreads();
    const int V = Vsh;

    // Gather sorted boxes for the valid prefix
    for (int t = tid; t < V; t += blockDim.x) {
        const float* bp = boxes_fg + (size_t)(cls * NP + id[t]) * 4;
        box[t] = make_float4(bp[0], bp[1], bp[2], bp[3]);
        supp[t] = 0;
    }
    __syncthreads();

    // Greedy NMS (legacy +1 IoU), sequential over i, parallel over j>i
    for (int i = 0; i < V; ++i) {
        if (!supp[i]) {
            const float4 bi = box[i];
            const float areai = (bi.z - bi.x + 1.0f) * (bi.w - bi.y + 1.0f);
            for (int t = i + 1 + tid; t < V; t += blockDim.x) {
                const float4 bj = box[t];
                const float areaj = (bj.z - bj.x + 1.0f) * (bj.w - bj.y + 1.0f);
                const float ltx = fmaxf(bi.x, bj.x);
                const float lty = fmaxf(bi.y, bj.y);
                const float rbx = fminf(bi.z, bj.z);
                const float rby = fminf(bi.w, bj.w);
                const float wq = fmaxf(rbx - ltx + 1.0f, 0.0f);
                const float hq = fmaxf(rby - lty + 1.0f, 0.0f);
                const float inter = wq * hq;
                const float iou = inter / (areai + areaj - inter);
                if (iou > NMS_THRESH) supp[t] = 1;
            }
        }
        __syncthreads();
    }

    // Compact kept (rank order) up to DET
    if (tid == 0) {
        int cnt = 0;
        for (int r = 0; r < V && cnt < DET; ++r)
            if (!supp[r]) keptRank[cnt++] = r;
        keptCnt = cnt;
    }
    __syncthreads();
    const int cnt = keptCnt;

    for (int t = tid; t < DET; t += blockDim.x) {
        const int slot = cls * DET + t;
        if (t < cnt) {
            const int r = keptRank[t];
            cand_score[slot] = s[r];
            const float4 b = box[r];
            cand_box[slot * 4 + 0] = b.x;
            cand_box[slot * 4 + 1] = b.y;
            cand_box[slot * 4 + 2] = b.z;
            cand_box[slot * 4 + 3] = b.w;
        } else {
            cand_score[slot] = -1.0f;
            cand_box[slot * 4 + 0] = 0.0f;
            cand_box[slot * 4 + 1] = 0.0f;
            cand_box[slot * 4 + 2] = 0.0f;
            cand_box[slot * 4 + 3] = 0.0f;
        }
    }
}

// ---------------------------------------------------------------------------
// Kernel 3: global top-100 over 8000 candidate slots + write outputs.
// 1 block, 1024 threads. Slot order (class-major, kept-rank) matches the
// reference's top_idx tie-break order.
// Output layout: boxes[100*4] | scores[100] | labels[100]  (all f32)
// ---------------------------------------------------------------------------
__global__ void topk_out_kernel(const float* __restrict__ cand_score,
                                const float* __restrict__ cand_box,
                                float* __restrict__ out) {
    __shared__ float          s[MSORT];
    __shared__ unsigned short id[MSORT];
    const int tid = threadIdx.x;  // 0..1023

    for (int t = tid; t < MSORT; t += blockDim.x) {
        s[t]  = (t < NCAND) ? cand_score[t] : -2.0f;
        id[t] = (unsigned short)t;
    }
    __syncthreads();

    for (int k = 2; k <= MSORT; k <<= 1) {
        for (int jj = k >> 1; jj > 0; jj >>= 1) {
            for (int t = tid; t < MSORT; t += blockDim.x) {
                const int ixj = t ^ jj;
                if (ixj > t) {
                    const float sa = s[t], sb = s[ixj];
                    const unsigned short ia = id[t], ib = id[ixj];
                    const bool tAfter = (sa < sb) || (sa == sb && ia > ib);
                    const bool dirAsc = ((t & k) == 0);
                    if (dirAsc ? tAfter : !tAfter) {
                        s[t] = sb; s[ixj] = sa;
                        id[t] = ib; id[ixj] = ia;
                    }
                }
            }
            __syncthreads();
        }
    }

    if (tid < DET) {
        const float sc  = s[tid];
        const int  slot = id[tid];
        const bool ok   = sc > 0.0f;
        float b0 = 0.0f, b1 = 0.0f, b2 = 0.0f, b3 = 0.0f, so = 0.0f;
        int lab = 0;
        if (ok) {
            b0 = cand_box[slot * 4 + 0];
            b1 = cand_box[slot * 4 + 1];
            b2 = cand_box[slot * 4 + 2];
            b3 = cand_box[slot * 4 + 3];
            so = sc;
            lab = slot / DET + 1;
        }
        out[tid * 4 + 0] = b0;
        out[tid * 4 + 1] = b1;
        out[tid * 4 + 2] = b2;
        out[tid * 4 + 3] = b3;
        out[4 * DET + tid] = so;
        out[5 * DET + tid] = (float)lab;
    }
}

// ---------------------------------------------------------------------------
extern "C" void kernel_launch(void* const* d_in, const int* in_sizes, int n_in,
                              void* d_out, int out_size, void* d_ws, size_t ws_size,
                              hipStream_t stream) {
    (void)in_sizes; (void)n_in; (void)out_size; (void)ws_size;

    const float* class_logits   = (const float*)d_in[0];  // [NP, NC]
    const float* box_regression = (const float*)d_in[1];  // [NP, 4*NC]
    const float* proposals      = (const float*)d_in[2];  // [NP, 4]
    float* out = (float*)d_out;                           // 600 floats

    // Workspace layout (floats)
    float* ws        = (float*)d_ws;
    float* scores_fg = ws;                                   // CF*NP        = 81920
    float* boxes_fg  = scores_fg + (size_t)CF * NP;          // CF*NP*4      = 327680
    float* cand_sc   = boxes_fg + (size_t)CF * NP * 4;       // NCAND        = 8000
    float* cand_bx   = cand_sc + NCAND;                      // NCAND*4      = 32000

    softmax_decode_kernel<<<dim3(NP), dim3(128), 0, stream>>>(
        class_logits, box_regression, proposals, scores_fg, boxes_fg);

    class_nms_kernel<<<dim3(CF), dim3(256), 0, stream>>>(
        scores_fg, boxes_fg, cand_sc, cand_bx);

    topk_out_kernel<<<dim3(1), dim3(1024), 0, stream>>>(cand_sc, cand_bx, out);
}

// Round 2
// 124.733 us; speedup vs baseline: 2.2490x; 2.2490x over previous
//
#include <hip/hip_runtime.h>
#include <hip/hip_bf16.h>
#include <math.h>

#define NP 1024          // proposals
#define NC 81            // classes incl background
#define CF 80            // foreground classes
#define DET 100          // detections per image
#define SCORE_THRESH 0.05f
#define NMS_THRESH 0.5f
#define BBOX_CLIP 4.135166556742356f   // log(1000/16)
#define IMG_W 1333
#define IMG_H 800

#define NCAND (CF * DET)   // 8000 max compacted candidates

// ---------------------------------------------------------------------------
// Kernel 1: per-proposal softmax + box decode + clip. Wave-synchronous:
// one 64-lane wave per proposal, 4 proposals per 256-thread block.
// Lane l handles classes l and (64+l if l<17). No __syncthreads.
// Layouts: scores_fg class-major [c][i] (coalesced row loads in k2),
//          boxes_pg proposal-major float4 [i][c] (coalesced stores here).
// Block 0 additionally zeroes d_out (600 f) and the global candidate counter.
// ---------------------------------------------------------------------------
__global__ __launch_bounds__(256) void
softmax_decode_kernel(const float* __restrict__ logits,
                      const float* __restrict__ rel,
                      const float* __restrict__ props,
                      float* __restrict__ scores_fg,
                      float* __restrict__ boxes_pg,
                      float* __restrict__ out,
                      int* __restrict__ gK) {
    if (blockIdx.x == 0) {
        for (int t = threadIdx.x; t < 6 * DET; t += 256) out[t] = 0.0f;
        if (threadIdx.x == 0) *gK = 0;
    }

    const int wave = threadIdx.x >> 6;
    const int lane = threadIdx.x & 63;
    const int i = blockIdx.x * 4 + wave;          // proposal index (< NP always)

    // softmax over 81 logits: lane holds x0 = logit[lane], x1 = logit[64+lane]
    const float x0 = logits[i * NC + lane];
    const float x1 = (lane < NC - 64) ? logits[i * NC + 64 + lane] : -INFINITY;

    float m = fmaxf(x0, x1);
    for (int off = 32; off > 0; off >>= 1) m = fmaxf(m, __shfl_xor(m, off));

    const float e0 = expf(x0 - m);
    const float e1 = (lane < NC - 64) ? expf(x1 - m) : 0.0f;
    float sum = e0 + e1;
    for (int off = 32; off > 0; off >>= 1) sum += __shfl_xor(sum, off);

    // proposal geometry (uniform across wave -> scalar loads)
    const float px1 = props[i * 4 + 0];
    const float py1 = props[i * 4 + 1];
    const float px2 = props[i * 4 + 2];
    const float py2 = props[i * 4 + 3];
    const float w  = px2 - px1 + 1.0f;
    const float h  = py2 - py1 + 1.0f;
    const float cx = px1 + 0.5f * w;
    const float cy = py1 + 0.5f * h;

    const float4* rel4 = (const float4*)rel;   // [NP][NC] float4

    #pragma unroll
    for (int half = 0; half < 2; ++half) {
        const int c = half * 64 + lane;        // class index
        const float e = half ? e1 : e0;
        if (c >= 1 && c < NC) {
            scores_fg[(c - 1) * NP + i] = e / sum;

            const float4 r = rel4[i * NC + c];
            const float dx = r.x * 0.1f;
            const float dy = r.y * 0.1f;
            const float dw = fminf(r.z * 0.2f, BBOX_CLIP);
            const float dh = fminf(r.w * 0.2f, BBOX_CLIP);

            const float pcx = dx * w + cx;
            const float pcy = dy * h + cy;
            const float pw  = expf(dw) * w;
            const float ph  = expf(dh) * h;

            float bx1 = pcx - 0.5f * pw;
            float by1 = pcy - 0.5f * ph;
            float bx2 = pcx + 0.5f * pw - 1.0f;
            float by2 = pcy + 0.5f * ph - 1.0f;

            bx1 = fminf(fmaxf(bx1, 0.0f), (float)(IMG_W - 1));
            bx2 = fminf(fmaxf(bx2, 0.0f), (float)(IMG_W - 1));
            by1 = fminf(fmaxf(by1, 0.0f), (float)(IMG_H - 1));
            by2 = fminf(fmaxf(by2, 0.0f), (float)(IMG_H - 1));

            ((float4*)boxes_pg)[i * CF + (c - 1)] =
                make_float4(bx1, by1, bx2, by2);
        }
    }
}

// Wait: dx/10 must match reference exactly. r.x * 0.1f != r.x / 10.0f in
// floating point. Use division to stay bit-identical to the reference/R1.
// (The kernel above is superseded by the corrected version below.)

__global__ __launch_bounds__(256) void
softmax_decode_kernel_v2(const float* __restrict__ logits,
                         const float* __restrict__ rel,
                         const float* __restrict__ props,
                         float* __restrict__ scores_fg,
                         float* __restrict__ boxes_pg,
                         float* __restrict__ out,
                         int* __restrict__ gK) {
    if (blockIdx.x == 0) {
        for (int t = threadIdx.x; t < 6 * DET; t += 256) out[t] = 0.0f;
        if (threadIdx.x == 0) *gK = 0;
    }

    const int wave = threadIdx.x >> 6;
    const int lane = threadIdx.x & 63;
    const int i = blockIdx.x * 4 + wave;

    const float x0 = logits[i * NC + lane];
    const float x1 = (lane < NC - 64) ? logits[i * NC + 64 + lane] : -INFINITY;

    float m = fmaxf(x0, x1);
    for (int off = 32; off > 0; off >>= 1) m = fmaxf(m, __shfl_xor(m, off));

    const float e0 = expf(x0 - m);
    const float e1 = (lane < NC - 64) ? expf(x1 - m) : 0.0f;
    float sum = e0 + e1;
    for (int off = 32; off > 0; off >>= 1) sum += __shfl_xor(sum, off);

    const float px1 = props[i * 4 + 0];
    const float py1 = props[i * 4 + 1];
    const float px2 = props[i * 4 + 2];
    const float py2 = props[i * 4 + 3];
    const float w  = px2 - px1 + 1.0f;
    const float h  = py2 - py1 + 1.0f;
    const float cx = px1 + 0.5f * w;
    const float cy = py1 + 0.5f * h;

    const float4* rel4 = (const float4*)rel;

    #pragma unroll
    for (int half = 0; half < 2; ++half) {
        const int c = half * 64 + lane;
        const float e = half ? e1 : e0;
        if (c >= 1 && c < NC) {
            scores_fg[(c - 1) * NP + i] = e / sum;

            const float4 r = rel4[i * NC + c];
            const float dx = r.x / 10.0f;
            const float dy = r.y / 10.0f;
            const float dw = fminf(r.z / 5.0f, BBOX_CLIP);
            const float dh = fminf(r.w / 5.0f, BBOX_CLIP);

            const float pcx = dx * w + cx;
            const float pcy = dy * h + cy;
            const float pw  = expf(dw) * w;
            const float ph  = expf(dh) * h;

            float bx1 = pcx - 0.5f * pw;
            float by1 = pcy - 0.5f * ph;
            float bx2 = pcx + 0.5f * pw - 1.0f;
            float by2 = pcy + 0.5f * ph - 1.0f;

            bx1 = fminf(fmaxf(bx1, 0.0f), (float)(IMG_W - 1));
            bx2 = fminf(fmaxf(bx2, 0.0f), (float)(IMG_W - 1));
            by1 = fminf(fmaxf(by1, 0.0f), (float)(IMG_H - 1));
            by2 = fminf(fmaxf(by2, 0.0f), (float)(IMG_H - 1));

            ((float4*)boxes_pg)[i * CF + (c - 1)] =
                make_float4(bx1, by1, bx2, by2);
        }
    }
}

// ---------------------------------------------------------------------------
// Kernel 2: per-class threshold-compact -> small bitonic sort -> greedy NMS
// -> append kept (<=DET) candidates to global list (u64 key + float4 box).
// Key = (float_bits(score) << 16) | (65535 - slot): monotone encoding of
// (score desc, slot asc); slot = cls*DET + keptRank preserves the reference's
// flat-index tie-break order. grid = CF blocks x 256 threads.
// ---------------------------------------------------------------------------
__global__ __launch_bounds__(256) void
class_nms_kernel(const float* __restrict__ scores_fg,
                 const float* __restrict__ boxes_pg,
                 unsigned long long* __restrict__ gkeys,
                 float4* __restrict__ gboxes,
                 int* __restrict__ gK) {
    const int cls = blockIdx.x;
    const int tid = threadIdx.x;

    __shared__ float          vs[NP];
    __shared__ unsigned short vid[NP];
    __shared__ float4         vbox[NP];
    __shared__ unsigned char  supp[NP];
    __shared__ int            cntSh;
    __shared__ int            keptRank[DET];
    __shared__ int            keptCnt;
    __shared__ int            baseSh;

    if (tid == 0) cntSh = 0;
    __syncthreads();

    // threshold compaction (order-agnostic; sort restores determinism)
    {
        const float4 v = ((const float4*)(scores_fg + cls * NP))[tid];
        if (v.x > SCORE_THRESH) { int p = atomicAdd(&cntSh, 1); vs[p] = v.x; vid[p] = (unsigned short)(4 * tid + 0); }
        if (v.y > SCORE_THRESH) { int p = atomicAdd(&cntSh, 1); vs[p] = v.y; vid[p] = (unsigned short)(4 * tid + 1); }
        if (v.z > SCORE_THRESH) { int p = atomicAdd(&cntSh, 1); vs[p] = v.z; vid[p] = (unsigned short)(4 * tid + 2); }
        if (v.w > SCORE_THRESH) { int p = atomicAdd(&cntSh, 1); vs[p] = v.w; vid[p] = (unsigned short)(4 * tid + 3); }
    }
    __syncthreads();
    const int cnt = cntSh;

    // next pow2 >= cnt
    int msz = 1;
    while (msz < cnt) msz <<= 1;
    for (int t = cnt + tid; t < msz; t += 256) { vs[t] = -1.0f; vid[t] = 0xFFFF; }
    __syncthreads();

    // bitonic sort over msz: score desc, id asc on ties (stable argsort(-s))
    for (int k = 2; k <= msz; k <<= 1) {
        for (int jj = k >> 1; jj > 0; jj >>= 1) {
            for (int t = tid; t < msz; t += 256) {
                const int ixj = t ^ jj;
                if (ixj > t) {
                    const float sa = vs[t], sb = vs[ixj];
                    const unsigned short ia = vid[t], ib = vid[ixj];
                    const bool tAfter = (sa < sb) || (sa == sb && ia > ib);
                    const bool dirAsc = ((t & k) == 0);
                    if (dirAsc ? tAfter : !tAfter) {
                        vs[t] = sb; vs[ixj] = sa;
                        vid[t] = ib; vid[ixj] = ia;
                    }
                }
            }
            __syncthreads();
        }
    }

    // gather boxes for the valid (sorted) candidates
    for (int t = tid; t < cnt; t += 256) {
        vbox[t] = ((const float4*)boxes_pg)[(int)vid[t] * CF + cls];
        supp[t] = 0;
    }
    __syncthreads();

    // greedy NMS (legacy +1 IoU): sequential over i, parallel over j>i
    for (int i = 0; i < cnt; ++i) {
        if (!supp[i]) {
            const float4 bi = vbox[i];
            const float areai = (bi.z - bi.x + 1.0f) * (bi.w - bi.y + 1.0f);
            for (int t = i + 1 + tid; t < cnt; t += 256) {
                const float4 bj = vbox[t];
                const float areaj = (bj.z - bj.x + 1.0f) * (bj.w - bj.y + 1.0f);
                const float ltx = fmaxf(bi.x, bj.x);
                const float lty = fmaxf(bi.y, bj.y);
                const float rbx = fminf(bi.z, bj.z);
                const float rby = fminf(bi.w, bj.w);
                const float wq = fmaxf(rbx - ltx + 1.0f, 0.0f);
                const float hq = fmaxf(rby - lty + 1.0f, 0.0f);
                const float inter = wq * hq;
                const float iou = inter / (areai + areaj - inter);
                if (iou > NMS_THRESH) supp[t] = 1;
            }
        }
        __syncthreads();
    }

    // compact kept in rank order, cap at DET (lossless for global top-DET)
    if (tid == 0) {
        int c2 = 0;
        for (int r = 0; r < cnt && c2 < DET; ++r)
            if (!supp[r]) keptRank[c2++] = r;
        keptCnt = c2;
        baseSh = atomicAdd(gK, c2);     // device-scope reserve
    }
    __syncthreads();

    const int kc = keptCnt, base = baseSh;
    for (int t = tid; t < kc; t += 256) {
        const int r = keptRank[t];
        const int slot = cls * DET + t;
        const unsigned long long key =
            ((unsigned long long)__float_as_uint(vs[r]) << 16) |
            (unsigned long long)(65535 - slot);
        gkeys[base + t] = key;
        gboxes[base + t] = vbox[r];
    }
}

// ---------------------------------------------------------------------------
// Kernel 3: rank-count top-DET over K compacted candidates.
// rank_i = #{j : key_j > key_i}; ranks are dense & unique, so each out slot
// 0..min(K,DET)-1 gets exactly one writer; slots >= K stay zero (kernel 1).
// grid = ceil(NCAND/64) blocks x 64 threads (1 wave/CU).
// ---------------------------------------------------------------------------
__global__ __launch_bounds__(64) void
topk_out_kernel(const unsigned long long* __restrict__ gkeys,
                const float4* __restrict__ gboxes,
                const int* __restrict__ gK,
                float* __restrict__ out) {
    const int K = *gK;
    if ((int)blockIdx.x * 64 >= K) return;

    __shared__ __align__(16) unsigned long long keys[NCAND];
    for (int t = threadIdx.x; t < K; t += 64) keys[t] = gkeys[t];
    __syncthreads();

    const int g = blockIdx.x * 64 + threadIdx.x;
    if (g < K) {
        const unsigned long long my = keys[g];
        int rank = 0;
        for (int j = 0; j < K; ++j) rank += (keys[j] > my) ? 1 : 0;
        if (rank < DET) {
            const float sc  = __uint_as_float((unsigned)(my >> 16));
            const int  slot = 65535 - (int)(my & 0xFFFFull);
            const float4 b = gboxes[g];
            out[rank * 4 + 0] = b.x;
            out[rank * 4 + 1] = b.y;
            out[rank * 4 + 2] = b.z;
            out[rank * 4 + 3] = b.w;
            out[4 * DET + rank] = sc;                       // score (>0 always)
            out[5 * DET + rank] = (float)(slot / DET + 1);  // label
        }
    }
}

// ---------------------------------------------------------------------------
extern "C" void kernel_launch(void* const* d_in, const int* in_sizes, int n_in,
                              void* d_out, int out_size, void* d_ws, size_t ws_size,
                              hipStream_t stream) {
    (void)in_sizes; (void)n_in; (void)out_size; (void)ws_size;

    const float* class_logits   = (const float*)d_in[0];  // [NP, NC]
    const float* box_regression = (const float*)d_in[1];  // [NP, 4*NC]
    const float* proposals      = (const float*)d_in[2];  // [NP, 4]
    float* out = (float*)d_out;                           // 600 floats

    // Workspace layout (float units; alignment: all 16B-aligned offsets)
    float* ws        = (float*)d_ws;
    float* boxes_pg  = ws;                                    // NP*CF*4   = 327680
    float* gboxes_f  = boxes_pg + (size_t)NP * CF * 4;        // NCAND*4   =  32000
    float* gkeys_f   = gboxes_f + (size_t)NCAND * 4;          // NCAND*2   =  16000
    float* scores_fg = gkeys_f + (size_t)NCAND * 2;           // CF*NP     =  81920
    int*   gK        = (int*)(scores_fg + (size_t)CF * NP);   // 1

    unsigned long long* gkeys = (unsigned long long*)gkeys_f;
    float4* gboxes = (float4*)gboxes_f;

    softmax_decode_kernel_v2<<<dim3(NP / 4), dim3(256), 0, stream>>>(
        class_logits, box_regression, proposals, scores_fg, boxes_pg, out, gK);

    class_nms_kernel<<<dim3(CF), dim3(256), 0, stream>>>(
        scores_fg, boxes_pg, gkeys, gboxes, gK);

    topk_out_kernel<<<dim3((NCAND + 63) / 64), dim3(64), 0, stream>>>(
        gkeys, gboxes, gK, out);
}